// Round 1
// baseline (48.477 us; speedup 1.0000x reference)
//
#include <hip/hip_runtime.h>

#define BATCH 16
#define NUM_HEADS 32
#define NUM_KV 8
#define GQ 4            // query heads per kv head
#define HD 128
#define PAGE 256        // cache block size
#define MAXB 8
#define NSPLIT 8        // one split per page
#define QSCALE 0.08838834764831845f

// ws layout per (b,kv,split): [4 m][4 l][4*128 acc] = 520 floats
#define WS_STRIDE 520

__global__ __launch_bounds__(256) void pa_partial(
    const float* __restrict__ q,
    const float* __restrict__ knew,
    const float* __restrict__ vnew,
    const float* __restrict__ kc,
    const float* __restrict__ vc,
    const int* __restrict__ block_tables,
    const int* __restrict__ context_lens,
    float* __restrict__ ws)
{
  int blk = blockIdx.x;
  int split = blk & 7;
  int kv = (blk >> 3) & 7;
  int b = blk >> 6;
  int ctx = context_lens[b];
  int start = split * PAGE;
  if (start >= ctx) return;           // uniform over block
  int n = min(PAGE, ctx - start);
  int page = block_tables[b * MAXB + split];

  int tid = threadIdx.x;
  int w = tid >> 6;        // wave 0..3
  int lane = tid & 63;
  int grp = lane >> 4;     // 16-lane token group, 0..3
  int j = lane & 15;       // dim slice: dims [j*8, j*8+8)

  // load q for the 4 query heads of this kv head, pre-scaled
  float qr[GQ][8];
  #pragma unroll
  for (int g = 0; g < GQ; ++g) {
    const float* qp = q + ((size_t)(b * NUM_HEADS + kv * GQ + g)) * HD + j * 8;
    float4 a = *(const float4*)(qp);
    float4 c = *(const float4*)(qp + 4);
    qr[g][0]=a.x*QSCALE; qr[g][1]=a.y*QSCALE; qr[g][2]=a.z*QSCALE; qr[g][3]=a.w*QSCALE;
    qr[g][4]=c.x*QSCALE; qr[g][5]=c.y*QSCALE; qr[g][6]=c.z*QSCALE; qr[g][7]=c.w*QSCALE;
  }

  float m[GQ], l[GQ], acc[GQ][8];
  #pragma unroll
  for (int g = 0; g < GQ; ++g) {
    m[g] = -1e30f; l[g] = 0.f;
    #pragma unroll
    for (int e = 0; e < 8; ++e) acc[g][e] = 0.f;
  }

  const float* knew_row = knew + (size_t)(b * NUM_KV + kv) * HD;
  const float* vnew_row = vnew + (size_t)(b * NUM_KV + kv) * HD;

  int iters = (n + 15) >> 4;   // 16 tokens per block iteration (4 waves x 4 groups)
  for (int i = 0; i < iters; ++i) {
    int tl = i * 16 + w * 4 + grp;      // token within page
    int tg = start + tl;                // token within sequence
    bool valid = tl < n;

    const float* krow;
    const float* vrow;
    if (tg == ctx - 1) {                // current-step token: take from k/v inputs
      krow = knew_row;
      vrow = vnew_row;
    } else {
      size_t off = ((size_t)(page * PAGE + (tl & 255)) * NUM_KV + kv) * HD;
      krow = kc + off;
      vrow = vc + off;
    }
    float4 k0 = *(const float4*)(krow + j * 8);
    float4 k1 = *(const float4*)(krow + j * 8 + 4);
    float4 v0 = *(const float4*)(vrow + j * 8);
    float4 v1 = *(const float4*)(vrow + j * 8 + 4);
    float kk[8] = {k0.x,k0.y,k0.z,k0.w,k1.x,k1.y,k1.z,k1.w};
    float vv[8] = {v0.x,v0.y,v0.z,v0.w,v1.x,v1.y,v1.z,v1.w};

    #pragma unroll
    for (int g = 0; g < GQ; ++g) {
      float s = 0.f;
      #pragma unroll
      for (int e = 0; e < 8; ++e) s += qr[g][e] * kk[e];
      // reduce over the 16 lanes of this token group
      s += __shfl_xor(s, 1);
      s += __shfl_xor(s, 2);
      s += __shfl_xor(s, 4);
      s += __shfl_xor(s, 8);
      if (valid) {
        float mn = fmaxf(m[g], s);
        float p  = __expf(s - mn);
        float sc = __expf(m[g] - mn);
        m[g] = mn;
        l[g] = l[g] * sc + p;
        #pragma unroll
        for (int e = 0; e < 8; ++e) acc[g][e] = acc[g][e] * sc + p * vv[e];
      }
    }
  }

  // merge the 4 token-groups within each wave (butterfly over lane masks 16, 32)
  #pragma unroll
  for (int g = 0; g < GQ; ++g) {
    #pragma unroll
    for (int mask = 16; mask <= 32; mask <<= 1) {
      float mo = __shfl_xor(m[g], mask);
      float lo = __shfl_xor(l[g], mask);
      float mn = fmaxf(m[g], mo);
      float ea = __expf(m[g] - mn);
      float eb = __expf(mo   - mn);
      l[g] = l[g] * ea + lo * eb;
      #pragma unroll
      for (int e = 0; e < 8; ++e) {
        float ao = __shfl_xor(acc[g][e], mask);
        acc[g][e] = acc[g][e] * ea + ao * eb;
      }
      m[g] = mn;
    }
  }

  // cross-wave merge via LDS
  __shared__ float s_m[4][GQ], s_l[4][GQ];
  __shared__ float s_acc[4][GQ][HD];
  if (lane < 16) {
    #pragma unroll
    for (int g = 0; g < GQ; ++g) {
      #pragma unroll
      for (int e = 0; e < 8; ++e) s_acc[w][g][j * 8 + e] = acc[g][e];
      if (j == 0) { s_m[w][g] = m[g]; s_l[w][g] = l[g]; }
    }
  }
  __syncthreads();

  float* outp = ws + (size_t)((b * NUM_KV + kv) * NSPLIT + split) * WS_STRIDE;
  for (int idx = tid; idx < GQ * HD; idx += 256) {
    int g = idx >> 7;
    int d = idx & 127;
    float M = fmaxf(fmaxf(s_m[0][g], s_m[1][g]), fmaxf(s_m[2][g], s_m[3][g]));
    float e0 = __expf(s_m[0][g] - M);
    float e1 = __expf(s_m[1][g] - M);
    float e2 = __expf(s_m[2][g] - M);
    float e3 = __expf(s_m[3][g] - M);
    float A = s_acc[0][g][d]*e0 + s_acc[1][g][d]*e1 + s_acc[2][g][d]*e2 + s_acc[3][g][d]*e3;
    outp[8 + idx] = A;
    if (d == 0) {
      float Ls = s_l[0][g]*e0 + s_l[1][g]*e1 + s_l[2][g]*e2 + s_l[3][g]*e3;
      outp[g] = M;
      outp[GQ + g] = Ls;
    }
  }
}

__global__ __launch_bounds__(128) void pa_reduce(
    const float* __restrict__ ws,
    const int* __restrict__ context_lens,
    float* __restrict__ out)
{
  int blk = blockIdx.x;     // (b, kv, g)
  int g  = blk & 3;
  int kv = (blk >> 2) & 7;
  int b  = blk >> 5;
  int d  = threadIdx.x;
  int ctx = context_lens[b];
  int ns = (ctx + PAGE - 1) / PAGE;
  const float* base = ws + (size_t)((b * NUM_KV + kv) * NSPLIT) * WS_STRIDE;

  float M = -1e30f;
  for (int s = 0; s < ns; ++s) M = fmaxf(M, base[s * WS_STRIDE + g]);
  float Lsum = 0.f, A = 0.f;
  for (int s = 0; s < ns; ++s) {
    float e = __expf(base[s * WS_STRIDE + g] - M);
    Lsum += base[s * WS_STRIDE + GQ + g] * e;
    A    += base[s * WS_STRIDE + 8 + g * HD + d] * e;
  }
  out[((size_t)(b * NUM_HEADS) + kv * GQ + g) * HD + d] = A / Lsum;
}

extern "C" void kernel_launch(void* const* d_in, const int* in_sizes, int n_in,
                              void* d_out, int out_size, void* d_ws, size_t ws_size,
                              hipStream_t stream) {
  const float* q  = (const float*)d_in[0];
  const float* k  = (const float*)d_in[1];
  const float* v  = (const float*)d_in[2];
  const float* kc = (const float*)d_in[3];
  const float* vc = (const float*)d_in[4];
  const int* block_tables = (const int*)d_in[5];
  const int* context_lens = (const int*)d_in[6];
  // d_in[7] = slot_mapping: not needed (new-token position derived from context_lens)

  float* ws = (float*)d_ws;
  float* out = (float*)d_out;

  pa_partial<<<BATCH * NUM_KV * NSPLIT, 256, 0, stream>>>(
      q, k, v, kc, vc, block_tables, context_lens, ws);
  pa_reduce<<<BATCH * NUM_KV * GQ, 128, 0, stream>>>(ws, context_lens, out);
}